// Round 1
// baseline (626.894 us; speedup 1.0000x reference)
//
#include <hip/hip_runtime.h>
#include <hip/hip_bf16.h>

#define Bb 4
#define Cc 256
#define Nn 32768

// ---------------- row sums: sx[b,c] = sum_n x[b,c,n]; sy likewise ------------
__global__ __launch_bounds__(256) void k_rowsum(const float* __restrict__ x,
                                                const float* __restrict__ y,
                                                float* __restrict__ sx,
                                                float* __restrict__ sy) {
    int bid = blockIdx.x;              // 0..2047
    int row = bid & 1023;              // b*C + c
    const float* src = (bid < 1024 ? x : y) + (size_t)row * Nn;
    float* dst = (bid < 1024 ? sx : sy) + row;
    int tid = threadIdx.x;
    float s = 0.f;
    const float4* s4 = (const float4*)src;
    for (int i = tid; i < Nn / 4; i += 256) {
        float4 v = s4[i];
        s += v.x + v.y + v.z + v.w;
    }
    __shared__ float red[256];
    red[tid] = s; __syncthreads();
    for (int st = 128; st > 0; st >>= 1) {
        if (tid < st) red[tid] += red[tid + st];
        __syncthreads();
    }
    if (tid == 0) *dst = red[0];
}

// ---------------- S partials: part[b][ks][64-tile r][64-tile c] --------------
// S[b,c,c'] = sum_n x[b,c,n] * y[b,c',n]   (split-K, deterministic reduce after)
__global__ __launch_bounds__(256) void k_xyT(const float* __restrict__ x,
                                             const float* __restrict__ y,
                                             float* __restrict__ part,
                                             int split, int kbsz) {
    int bid = blockIdx.x;
    int ct = bid & 3;
    int rt = (bid >> 2) & 3;
    int rest = bid >> 4;
    int ks = rest % split;
    int b  = rest / split;

    const float* X = x + (size_t)b * Cc * Nn + (size_t)(rt * 64) * Nn + (size_t)ks * kbsz;
    const float* Y = y + (size_t)b * Cc * Nn + (size_t)(ct * 64) * Nn + (size_t)ks * kbsz;

    __shared__ float Xs[32][68];   // [k][row], pad 68 (16B-aligned rows)
    __shared__ float Ys[32][68];

    int tid = threadIdx.x;
    int tx = tid & 15, ty = tid >> 4;
    float acc[4][4] = {};

    for (int kb = 0; kb < kbsz; kb += 32) {
        #pragma unroll
        for (int p = 0; p < 2; ++p) {
            int idx = p * 256 + tid;           // 0..511
            int row = idx >> 3;                // 0..63
            int c4  = (idx & 7) << 2;          // 0..28
            float4 xv = *(const float4*)(X + (size_t)row * Nn + kb + c4);
            float4 yv = *(const float4*)(Y + (size_t)row * Nn + kb + c4);
            Xs[c4 + 0][row] = xv.x; Xs[c4 + 1][row] = xv.y;
            Xs[c4 + 2][row] = xv.z; Xs[c4 + 3][row] = xv.w;
            Ys[c4 + 0][row] = yv.x; Ys[c4 + 1][row] = yv.y;
            Ys[c4 + 2][row] = yv.z; Ys[c4 + 3][row] = yv.w;
        }
        __syncthreads();
        #pragma unroll
        for (int k = 0; k < 32; ++k) {
            float4 av = *(const float4*)&Xs[k][4 * ty];
            float4 bv = *(const float4*)&Ys[k][4 * tx];
            float a[4] = {av.x, av.y, av.z, av.w};
            float bbv[4] = {bv.x, bv.y, bv.z, bv.w};
            #pragma unroll
            for (int i2 = 0; i2 < 4; ++i2)
                #pragma unroll
                for (int j2 = 0; j2 < 4; ++j2)
                    acc[i2][j2] += a[i2] * bbv[j2];
        }
        __syncthreads();
    }

    float* P = part + (((size_t)b * split + ks) * Cc + rt * 64 + 4 * ty) * Cc + ct * 64 + 4 * tx;
    #pragma unroll
    for (int i2 = 0; i2 < 4; ++i2) {
        float4 o; o.x = acc[i2][0]; o.y = acc[i2][1]; o.z = acc[i2][2]; o.w = acc[i2][3];
        *(float4*)(P + (size_t)i2 * Cc) = o;
    }
}

__global__ __launch_bounds__(256) void k_reduceS(const float* __restrict__ part,
                                                 float* __restrict__ S, int split) {
    int t = blockIdx.x * 256 + threadIdx.x;   // 0..262143
    int b = t >> 16;
    int rc = t & 65535;
    float s = 0.f;
    for (int ks = 0; ks < split; ++ks)
        s += part[(((size_t)b * split + ks) << 16) + rc];
    S[t] = s;
}

// qx[b,i] = Wq[i,:]·sx[b,:];  ky[b,j] = Wk[j,:]·sy[b,:]
__global__ __launch_bounds__(256) void k_qxky(const float* __restrict__ Wq,
                                              const float* __restrict__ Wk,
                                              const float* __restrict__ sx,
                                              const float* __restrict__ sy,
                                              float* __restrict__ qx,
                                              float* __restrict__ ky) {
    int t = blockIdx.x * 256 + threadIdx.x;   // 0..2047
    int which = t >> 10;
    int b = (t >> 8) & 3;
    int r = t & 255;
    const float* W  = which ? Wk : Wq;
    const float* sv = which ? sy : sx;
    float* dst      = which ? ky : qx;
    float s = 0.f;
    #pragma unroll 4
    for (int c = 0; c < Cc; ++c) s += W[r * Cc + c] * sv[b * Cc + c];
    dst[b * Cc + r] = s;
}

// T1[b,c,j] = sum_d S[b,c,d] * Wk[j,d]
__global__ __launch_bounds__(256) void k_T1(const float* __restrict__ S,
                                            const float* __restrict__ Wk,
                                            float* __restrict__ T1) {
    int b = blockIdx.x >> 8;
    int c = blockIdx.x & 255;
    int j = threadIdx.x;
    __shared__ float srow[256];
    srow[j] = S[((size_t)b * Cc + c) * Cc + j];
    __syncthreads();
    const float4* wk4 = (const float4*)(Wk + (size_t)j * Cc);
    const float4* sr4 = (const float4*)srow;
    float s = 0.f;
    #pragma unroll 4
    for (int d = 0; d < Cc / 4; ++d) {
        float4 a = sr4[d]; float4 w = wk4[d];
        s += a.x * w.x + a.y * w.y + a.z * w.z + a.w * w.w;
    }
    T1[((size_t)b * Cc + c) * Cc + j] = s;
}

// scores + softmax + cbias:  one block per (b,i) row
__global__ __launch_bounds__(256) void k_scores_softmax(const float* __restrict__ T1,
                                                        const float* __restrict__ Wq,
                                                        const float* __restrict__ bq,
                                                        const float* __restrict__ bk,
                                                        const float* __restrict__ qx,
                                                        const float* __restrict__ ky,
                                                        const float* __restrict__ bv,
                                                        float* __restrict__ Wt,
                                                        float* __restrict__ cbias) {
    int b = blockIdx.x >> 8;
    int i = blockIdx.x & 255;
    int j = threadIdx.x;
    __shared__ float wq[256];
    wq[j] = Wq[i * Cc + j];
    __syncthreads();
    const float* t1 = T1 + (size_t)b * Cc * Cc + j;
    float s = 0.f;
    #pragma unroll 4
    for (int c = 0; c < Cc; ++c) s += wq[c] * t1[(size_t)c * Cc];
    s += qx[b * Cc + i] * bk[j] + bq[i] * (ky[b * Cc + j] + 32768.0f * bk[j]);

    __shared__ float red[256];
    red[j] = s; __syncthreads();
    for (int st = 128; st > 0; st >>= 1) {
        if (j < st) red[j] = fmaxf(red[j], red[j + st]);
        __syncthreads();
    }
    float mx = red[0];
    __syncthreads();
    float e = expf(s - mx);
    red[j] = e; __syncthreads();
    for (int st = 128; st > 0; st >>= 1) {
        if (j < st) red[j] += red[j + st];
        __syncthreads();
    }
    float w = e / red[0];
    Wt[((size_t)b * Cc + i) * Cc + j] = w;
    __syncthreads();
    red[j] = w * bv[j]; __syncthreads();
    for (int st = 128; st > 0; st >>= 1) {
        if (j < st) red[j] += red[j + st];
        __syncthreads();
    }
    if (j == 0) cbias[b * Cc + i] = red[0];
}

// M[b,i,c] = sum_j Wt[b,i,j] * Wv[j,c]
__global__ __launch_bounds__(256) void k_M(const float* __restrict__ Wt,
                                           const float* __restrict__ Wv,
                                           float* __restrict__ M) {
    int b = blockIdx.x >> 8;
    int i = blockIdx.x & 255;
    int c = threadIdx.x;
    __shared__ float wrow[256];
    wrow[c] = Wt[((size_t)b * Cc + i) * Cc + c];
    __syncthreads();
    float m = 0.f;
    #pragma unroll 4
    for (int j = 0; j < Cc; ++j) m += wrow[j] * Wv[(size_t)j * Cc + c];
    M[((size_t)b * Cc + i) * Cc + c] = m;
}

// out[b,i,n] = sum_c M[b,i,c] * y[b,c,n] + cbias[b,i]
__global__ __launch_bounds__(256) void k_out(const float* __restrict__ M,
                                             const float* __restrict__ y,
                                             const float* __restrict__ cb,
                                             float* __restrict__ out) {
    int bid = blockIdx.x;
    int nt = bid & 511;
    int it = (bid >> 9) & 3;
    int b  = bid >> 11;
    const float* Mb = M + ((size_t)b * Cc + it * 64) * Cc;
    const float* Yb = y + (size_t)b * Cc * Nn + nt * 64;

    __shared__ float Ms[32][68];   // [c][i]
    __shared__ float Ys[32][68];   // [c][n]
    int tid = threadIdx.x;
    int tx = tid & 15, ty = tid >> 4;
    float acc[4][4] = {};

    for (int kb = 0; kb < Cc; kb += 32) {
        #pragma unroll
        for (int p = 0; p < 2; ++p) {
            int idx = p * 256 + tid;      // 0..511
            int row = idx >> 3;           // i: 0..63
            int c4  = (idx & 7) << 2;     // c: 0..28
            float4 mv = *(const float4*)(Mb + (size_t)row * Cc + kb + c4);
            Ms[c4 + 0][row] = mv.x; Ms[c4 + 1][row] = mv.y;
            Ms[c4 + 2][row] = mv.z; Ms[c4 + 3][row] = mv.w;
        }
        #pragma unroll
        for (int p = 0; p < 2; ++p) {
            int idx = p * 256 + tid;      // 0..511
            int row = idx >> 4;           // c: 0..31
            int n4  = (idx & 15) << 2;    // n: 0..60
            *(float4*)&Ys[row][n4] = *(const float4*)(Yb + (size_t)(kb + row) * Nn + n4);
        }
        __syncthreads();
        #pragma unroll
        for (int k = 0; k < 32; ++k) {
            float4 av = *(const float4*)&Ms[k][4 * ty];
            float4 bv = *(const float4*)&Ys[k][4 * tx];
            float a[4] = {av.x, av.y, av.z, av.w};
            float bbv[4] = {bv.x, bv.y, bv.z, bv.w};
            #pragma unroll
            for (int i2 = 0; i2 < 4; ++i2)
                #pragma unroll
                for (int j2 = 0; j2 < 4; ++j2)
                    acc[i2][j2] += a[i2] * bbv[j2];
        }
        __syncthreads();
    }

    int i0 = it * 64 + 4 * ty;
    int n0 = nt * 64 + 4 * tx;
    float* O = out + ((size_t)b * Cc + i0) * Nn + n0;
    #pragma unroll
    for (int i2 = 0; i2 < 4; ++i2) {
        float cbv = cb[b * Cc + i0 + i2];
        float4 o;
        o.x = acc[i2][0] + cbv; o.y = acc[i2][1] + cbv;
        o.z = acc[i2][2] + cbv; o.w = acc[i2][3] + cbv;
        *(float4*)(O + (size_t)i2 * Nn) = o;
    }
}

extern "C" void kernel_launch(void* const* d_in, const int* in_sizes, int n_in,
                              void* d_out, int out_size, void* d_ws, size_t ws_size,
                              hipStream_t stream) {
    const float* x  = (const float*)d_in[0];
    const float* y  = (const float*)d_in[1];
    const float* Wq = (const float*)d_in[2];
    const float* bq = (const float*)d_in[3];
    const float* Wk = (const float*)d_in[4];
    const float* bk = (const float*)d_in[5];
    const float* Wv = (const float*)d_in[6];
    const float* bv = (const float*)d_in[7];
    float* out = (float*)d_out;

    float* ws = (float*)d_ws;
    size_t off = 0;
    float* S  = ws + off; off += (size_t)Bb * Cc * Cc;
    float* sx = ws + off; off += Bb * Cc;
    float* sy = ws + off; off += Bb * Cc;
    float* qx = ws + off; off += Bb * Cc;
    float* ky = ws + off; off += Bb * Cc;
    float* T1 = ws + off; off += (size_t)Bb * Cc * Cc;
    float* Wt = ws + off; off += (size_t)Bb * Cc * Cc;
    float* Mm = ws + off; off += (size_t)Bb * Cc * Cc;
    float* cb = ws + off; off += Bb * Cc;
    float* part = ws + off;

    size_t avail = ws_size / 4 - off;
    int split = 16;
    while (split > 1 && (size_t)split * Bb * Cc * Cc > avail) split >>= 1;

    k_rowsum<<<2048, 256, 0, stream>>>(x, y, sx, sy);
    k_xyT<<<Bb * split * 16, 256, 0, stream>>>(x, y, part, split, Nn / split);
    k_reduceS<<<1024, 256, 0, stream>>>(part, S, split);
    k_qxky<<<8, 256, 0, stream>>>(Wq, Wk, sx, sy, qx, ky);
    k_T1<<<1024, 256, 0, stream>>>(S, Wk, T1);
    k_scores_softmax<<<1024, 256, 0, stream>>>(T1, Wq, bq, bk, qx, ky, bv, Wt, cb);
    k_M<<<1024, 256, 0, stream>>>(Wt, Wv, Mm);
    k_out<<<8192, 256, 0, stream>>>(Mm, y, cb, out);
}

// Round 2
// 413.358 us; speedup vs baseline: 1.5166x; 1.5166x over previous
//
#include <hip/hip_runtime.h>

#define Bb 4
#define Cc 256
#define Nn 32768

typedef short s16x8 __attribute__((ext_vector_type(8)));
typedef float f32x4 __attribute__((ext_vector_type(4)));

__device__ __forceinline__ unsigned short bfh(float f) {
    union { float f; unsigned u; } c; c.f = f;
    unsigned u = c.u + 0x7fffu + ((c.u >> 16) & 1u);
    return (unsigned short)(u >> 16);
}
__device__ __forceinline__ float bf2f(unsigned short h) {
    union { unsigned u; float f; } c; c.u = ((unsigned)h) << 16;
    return c.f;
}
__device__ __forceinline__ int swz(int l) { return l ^ ((l >> 3) & 6); }

// ---------------- row sums: sx[b,c] = sum_n x[b,c,n]; sy likewise ------------
__global__ __launch_bounds__(256) void k_rowsum(const float* __restrict__ x,
                                                const float* __restrict__ y,
                                                float* __restrict__ sx,
                                                float* __restrict__ sy) {
    int bid = blockIdx.x;              // 0..2047
    int row = bid & 1023;              // b*C + c
    const float* src = (bid < 1024 ? x : y) + (size_t)row * Nn;
    float* dst = (bid < 1024 ? sx : sy) + row;
    int tid = threadIdx.x;
    float s = 0.f;
    const float4* s4 = (const float4*)src;
    for (int i = tid; i < Nn / 4; i += 256) {
        float4 v = s4[i];
        s += v.x + v.y + v.z + v.w;
    }
    __shared__ float red[256];
    red[tid] = s; __syncthreads();
    for (int st = 128; st > 0; st >>= 1) {
        if (tid < st) red[tid] += red[tid + st];
        __syncthreads();
    }
    if (tid == 0) *dst = red[0];
}

// ---------------- Gram partials via bf16x3 MFMA ------------------------------
// part[b][ks][gi][gj] += sum over k-slice of x[b,gi,k]*y[b,gj,k]
// Block: 256 thr = 4 waves (2x2 wave grid), computes 128 rows x 256 cols.
__global__ __launch_bounds__(256, 2) void k_gram(const float* __restrict__ x,
                                                 const float* __restrict__ y,
                                                 float* __restrict__ part,
                                                 int nsplit) {
    int bid = blockIdx.x;
    int half = bid & 1;
    int ks = (bid >> 1) % nsplit;
    int b = bid / (2 * nsplit);
    int Kblk = Nn / nsplit;

    const float* X = x + (size_t)b * Cc * Nn + (size_t)(half * 128) * Nn + (size_t)ks * Kblk;
    const float* Y = y + (size_t)b * Cc * Nn + (size_t)ks * Kblk;

    // fragment-linear LDS: frag = 64 lanes x 16B. X: 8 frags (128 rows), Y: 16.
    __shared__ __align__(16) short XH[4096], XL[4096];
    __shared__ __align__(16) short YH[8192], YL[8192];

    int tid = threadIdx.x;
    int lane = tid & 63;
    int wave = tid >> 6;
    int wr = wave >> 1, wc = wave & 1;

    int r = tid >> 1, kh = tid & 1;    // staging role: row r (0..127), k-half

    f32x4 acc[4][8];
    #pragma unroll
    for (int i = 0; i < 4; ++i)
        #pragma unroll
        for (int j = 0; j < 8; ++j)
            #pragma unroll
            for (int z = 0; z < 4; ++z) acc[i][j][z] = 0.f;

    for (int kb = 0; kb < Kblk; kb += 32) {
        // ---- stage x rows (128) ----
        {
            const float* src = X + (size_t)r * Nn + kb + kh * 16;
            float4 v0 = ((const float4*)src)[0];
            float4 v1 = ((const float4*)src)[1];
            float4 v2 = ((const float4*)src)[2];
            float4 v3 = ((const float4*)src)[3];
            float f[16] = {v0.x,v0.y,v0.z,v0.w, v1.x,v1.y,v1.z,v1.w,
                           v2.x,v2.y,v2.z,v2.w, v3.x,v3.y,v3.z,v3.w};
            int tr = r >> 4, rr = r & 15;
            int l0 = rr + 32 * kh;         // k chunk h=2*kh   -> lanes rr+16h
            int l1 = l0 + 16;              // k chunk h=2*kh+1
            s16x8 h0, h1, q0, q1;
            #pragma unroll
            for (int j = 0; j < 8; ++j) {
                unsigned short a = bfh(f[j]);
                h0[j] = (short)a;  q0[j] = (short)bfh(f[j] - bf2f(a));
                unsigned short bb = bfh(f[j + 8]);
                h1[j] = (short)bb; q1[j] = (short)bfh(f[j + 8] - bf2f(bb));
            }
            *(s16x8*)&XH[(tr * 64 + swz(l0)) * 8] = h0;
            *(s16x8*)&XH[(tr * 64 + swz(l1)) * 8] = h1;
            *(s16x8*)&XL[(tr * 64 + swz(l0)) * 8] = q0;
            *(s16x8*)&XL[(tr * 64 + swz(l1)) * 8] = q1;
        }
        // ---- stage y rows (256) ----
        #pragma unroll
        for (int p = 0; p < 2; ++p) {
            int ry = r + 128 * p;
            const float* src = Y + (size_t)ry * Nn + kb + kh * 16;
            float4 v0 = ((const float4*)src)[0];
            float4 v1 = ((const float4*)src)[1];
            float4 v2 = ((const float4*)src)[2];
            float4 v3 = ((const float4*)src)[3];
            float f[16] = {v0.x,v0.y,v0.z,v0.w, v1.x,v1.y,v1.z,v1.w,
                           v2.x,v2.y,v2.z,v2.w, v3.x,v3.y,v3.z,v3.w};
            int tc = ry >> 4, rr = ry & 15;
            int l0 = rr + 32 * kh;
            int l1 = l0 + 16;
            s16x8 h0, h1, q0, q1;
            #pragma unroll
            for (int j = 0; j < 8; ++j) {
                unsigned short a = bfh(f[j]);
                h0[j] = (short)a;  q0[j] = (short)bfh(f[j] - bf2f(a));
                unsigned short bb = bfh(f[j + 8]);
                h1[j] = (short)bb; q1[j] = (short)bfh(f[j + 8] - bf2f(bb));
            }
            *(s16x8*)&YH[(tc * 64 + swz(l0)) * 8] = h0;
            *(s16x8*)&YH[(tc * 64 + swz(l1)) * 8] = h1;
            *(s16x8*)&YL[(tc * 64 + swz(l0)) * 8] = q0;
            *(s16x8*)&YL[(tc * 64 + swz(l1)) * 8] = q1;
        }
        __syncthreads();
        // ---- compute ----
        {
            int sl = swz(lane);
            s16x8 ah[4], al[4];
            #pragma unroll
            for (int i = 0; i < 4; ++i) {
                int fr = (wr * 4 + i) * 64 + sl;
                ah[i] = *(const s16x8*)&XH[fr * 8];
                al[i] = *(const s16x8*)&XL[fr * 8];
            }
            #pragma unroll
            for (int j = 0; j < 8; ++j) {
                int fr = (wc * 8 + j) * 64 + sl;
                s16x8 bh = *(const s16x8*)&YH[fr * 8];
                s16x8 bl = *(const s16x8*)&YL[fr * 8];
                #pragma unroll
                for (int i = 0; i < 4; ++i) {
                    acc[i][j] = __builtin_amdgcn_mfma_f32_16x16x32_bf16(ah[i], bh, acc[i][j], 0, 0, 0);
                    acc[i][j] = __builtin_amdgcn_mfma_f32_16x16x32_bf16(ah[i], bl, acc[i][j], 0, 0, 0);
                    acc[i][j] = __builtin_amdgcn_mfma_f32_16x16x32_bf16(al[i], bh, acc[i][j], 0, 0, 0);
                }
            }
        }
        __syncthreads();
    }
    // ---- write partials (C/D: col = lane&15, row = (lane>>4)*4 + reg) ------
    float* P = part + ((size_t)b * nsplit + ks) * Cc * Cc;
    #pragma unroll
    for (int i = 0; i < 4; ++i)
        #pragma unroll
        for (int j = 0; j < 8; ++j)
            #pragma unroll
            for (int reg = 0; reg < 4; ++reg) {
                int gi = half * 128 + wr * 64 + i * 16 + (lane >> 4) * 4 + reg;
                int gj = wc * 128 + j * 16 + (lane & 15);
                P[(size_t)gi * Cc + gj] = acc[i][j][reg];
            }
}

__global__ __launch_bounds__(256) void k_reduceS(const float* __restrict__ part,
                                                 float* __restrict__ S, int split) {
    int t = blockIdx.x * 256 + threadIdx.x;   // 0..262143
    int b = t >> 16;
    int rc = t & 65535;
    float s = 0.f;
    for (int ks = 0; ks < split; ++ks)
        s += part[(((size_t)b * split + ks) << 16) + rc];
    S[t] = s;
}

// qx[b,i] = Wq[i,:]·sx[b,:];  ky[b,j] = Wk[j,:]·sy[b,:]
__global__ __launch_bounds__(256) void k_qxky(const float* __restrict__ Wq,
                                              const float* __restrict__ Wk,
                                              const float* __restrict__ sx,
                                              const float* __restrict__ sy,
                                              float* __restrict__ qx,
                                              float* __restrict__ ky) {
    int t = blockIdx.x * 256 + threadIdx.x;   // 0..2047
    int which = t >> 10;
    int b = (t >> 8) & 3;
    int r = t & 255;
    const float* W  = which ? Wk : Wq;
    const float* sv = which ? sy : sx;
    float* dst      = which ? ky : qx;
    float s = 0.f;
    #pragma unroll 4
    for (int c = 0; c < Cc; ++c) s += W[r * Cc + c] * sv[b * Cc + c];
    dst[b * Cc + r] = s;
}

// T1[b,c,j] = sum_d S[b,c,d] * Wk[j,d]
__global__ __launch_bounds__(256) void k_T1(const float* __restrict__ S,
                                            const float* __restrict__ Wk,
                                            float* __restrict__ T1) {
    int b = blockIdx.x >> 8;
    int c = blockIdx.x & 255;
    int j = threadIdx.x;
    __shared__ float srow[256];
    srow[j] = S[((size_t)b * Cc + c) * Cc + j];
    __syncthreads();
    const float4* wk4 = (const float4*)(Wk + (size_t)j * Cc);
    const float4* sr4 = (const float4*)srow;
    float s = 0.f;
    #pragma unroll 4
    for (int d = 0; d < Cc / 4; ++d) {
        float4 a = sr4[d]; float4 w = wk4[d];
        s += a.x * w.x + a.y * w.y + a.z * w.z + a.w * w.w;
    }
    T1[((size_t)b * Cc + c) * Cc + j] = s;
}

// scores + softmax + cbias:  one block per (b,i) row
__global__ __launch_bounds__(256) void k_scores_softmax(const float* __restrict__ T1,
                                                        const float* __restrict__ Wq,
                                                        const float* __restrict__ bq,
                                                        const float* __restrict__ bk,
                                                        const float* __restrict__ qx,
                                                        const float* __restrict__ ky,
                                                        const float* __restrict__ bv,
                                                        float* __restrict__ Wt,
                                                        float* __restrict__ cbias) {
    int b = blockIdx.x >> 8;
    int i = blockIdx.x & 255;
    int j = threadIdx.x;
    __shared__ float wq[256];
    wq[j] = Wq[i * Cc + j];
    __syncthreads();
    const float* t1 = T1 + (size_t)b * Cc * Cc + j;
    float s = 0.f;
    #pragma unroll 4
    for (int c = 0; c < Cc; ++c) s += wq[c] * t1[(size_t)c * Cc];
    s += qx[b * Cc + i] * bk[j] + bq[i] * (ky[b * Cc + j] + 32768.0f * bk[j]);

    __shared__ float red[256];
    red[j] = s; __syncthreads();
    for (int st = 128; st > 0; st >>= 1) {
        if (j < st) red[j] = fmaxf(red[j], red[j + st]);
        __syncthreads();
    }
    float mx = red[0];
    __syncthreads();
    float e = expf(s - mx);
    red[j] = e; __syncthreads();
    for (int st = 128; st > 0; st >>= 1) {
        if (j < st) red[j] += red[j + st];
        __syncthreads();
    }
    float w = e / red[0];
    Wt[((size_t)b * Cc + i) * Cc + j] = w;
    __syncthreads();
    red[j] = w * bv[j]; __syncthreads();
    for (int st = 128; st > 0; st >>= 1) {
        if (j < st) red[j] += red[j + st];
        __syncthreads();
    }
    if (j == 0) cbias[b * Cc + i] = red[0];
}

// M[b,i,c] = sum_j Wt[b,i,j] * Wv[j,c]   -> bf16
__global__ __launch_bounds__(256) void k_M(const float* __restrict__ Wt,
                                           const float* __restrict__ Wv,
                                           short* __restrict__ Mbf) {
    int b = blockIdx.x >> 8;
    int i = blockIdx.x & 255;
    int c = threadIdx.x;
    __shared__ float wrow[256];
    wrow[c] = Wt[((size_t)b * Cc + i) * Cc + c];
    __syncthreads();
    float m = 0.f;
    #pragma unroll 4
    for (int j = 0; j < Cc; ++j) m += wrow[j] * Wv[(size_t)j * Cc + c];
    Mbf[((size_t)b * Cc + i) * Cc + c] = (short)bfh(m);
}

// out[b,i,n] = sum_c M[b,i,c]*y[b,c,n] + cb[b,i]   (single-pass bf16 MFMA)
// Block: 4 waves; wave owns 32 n-cols (2 tiles), computes all 256 i-rows.
__global__ __launch_bounds__(256, 2) void k_out_mfma(const short* __restrict__ Mbf,
                                                     const float* __restrict__ y,
                                                     const float* __restrict__ cb,
                                                     float* __restrict__ out) {
    int tid = threadIdx.x;
    int lane = tid & 63;
    int wave = tid >> 6;
    int bid = blockIdx.x;           // 0..1023
    int b = bid >> 8, grp = bid & 255;
    int nbase = grp * 128 + wave * 32;
    const float* Y = y + (size_t)b * Cc * Nn;
    const short* M = Mbf + (size_t)b * Cc * Cc;

    f32x4 acc[16][2];
    #pragma unroll
    for (int ti = 0; ti < 16; ++ti)
        #pragma unroll
        for (int nb = 0; nb < 2; ++nb)
            #pragma unroll
            for (int z = 0; z < 4; ++z) acc[ti][nb][z] = 0.f;

    for (int s = 0; s < 8; ++s) {
        int c0 = 32 * s + 8 * (lane >> 4);
        s16x8 bf0, bf1;
        #pragma unroll
        for (int j = 0; j < 8; ++j) {
            float v0 = Y[(size_t)(c0 + j) * Nn + nbase + (lane & 15)];
            float v1 = Y[(size_t)(c0 + j) * Nn + nbase + 16 + (lane & 15)];
            bf0[j] = (short)bfh(v0);
            bf1[j] = (short)bfh(v1);
        }
        #pragma unroll
        for (int ti = 0; ti < 16; ++ti) {
            s16x8 af = *(const s16x8*)&M[(size_t)(ti * 16 + (lane & 15)) * Cc + c0];
            acc[ti][0] = __builtin_amdgcn_mfma_f32_16x16x32_bf16(af, bf0, acc[ti][0], 0, 0, 0);
            acc[ti][1] = __builtin_amdgcn_mfma_f32_16x16x32_bf16(af, bf1, acc[ti][1], 0, 0, 0);
        }
    }
    #pragma unroll
    for (int ti = 0; ti < 16; ++ti)
        #pragma unroll
        for (int nb = 0; nb < 2; ++nb)
            #pragma unroll
            for (int reg = 0; reg < 4; ++reg) {
                int i = ti * 16 + (lane >> 4) * 4 + reg;
                out[((size_t)b * Cc + i) * Nn + nbase + nb * 16 + (lane & 15)] =
                    acc[ti][nb][reg] + cb[b * Cc + i];
            }
}

extern "C" void kernel_launch(void* const* d_in, const int* in_sizes, int n_in,
                              void* d_out, int out_size, void* d_ws, size_t ws_size,
                              hipStream_t stream) {
    const float* x  = (const float*)d_in[0];
    const float* y  = (const float*)d_in[1];
    const float* Wq = (const float*)d_in[2];
    const float* bq = (const float*)d_in[3];
    const float* Wk = (const float*)d_in[4];
    const float* bk = (const float*)d_in[5];
    const float* Wv = (const float*)d_in[6];
    const float* bv = (const float*)d_in[7];
    float* out = (float*)d_out;

    float* ws = (float*)d_ws;
    size_t off = 0;
    float* S  = ws + off; off += (size_t)Bb * Cc * Cc;
    float* sx = ws + off; off += Bb * Cc;
    float* sy = ws + off; off += Bb * Cc;
    float* qx = ws + off; off += Bb * Cc;
    float* ky = ws + off; off += Bb * Cc;
    float* T1 = ws + off; off += (size_t)Bb * Cc * Cc;
    float* Wt = ws + off; off += (size_t)Bb * Cc * Cc;
    short* Mbf = (short*)(ws + off); off += (size_t)Bb * Cc * Cc / 2;
    float* cb = ws + off; off += Bb * Cc;
    float* part = ws + off;

    size_t avail = ws_size / 4 - off;
    int split = 64;
    while (split > 16 && (size_t)split * Bb * Cc * Cc > avail) split >>= 1;

    k_rowsum<<<2048, 256, 0, stream>>>(x, y, sx, sy);
    k_gram<<<Bb * split * 2, 256, 0, stream>>>(x, y, part, split);
    k_reduceS<<<1024, 256, 0, stream>>>(part, S, split);
    k_qxky<<<8, 256, 0, stream>>>(Wq, Wk, sx, sy, qx, ky);
    k_T1<<<1024, 256, 0, stream>>>(S, Wk, T1);
    k_scores_softmax<<<1024, 256, 0, stream>>>(T1, Wq, bq, bk, qx, ky, bv, Wt, cb);
    k_M<<<1024, 256, 0, stream>>>(Wt, Wv, Mbf);
    k_out_mfma<<<1024, 256, 0, stream>>>(Mbf, y, cb, out);
}

// Round 3
// 296.298 us; speedup vs baseline: 2.1158x; 1.3951x over previous
//
#include <hip/hip_runtime.h>

#define Bb 4
#define Cc 256
#define Nn 32768

typedef short s16x8 __attribute__((ext_vector_type(8)));
typedef float f32x4 __attribute__((ext_vector_type(4)));

__device__ __forceinline__ unsigned short bfh(float f) {
    union { float f; unsigned u; } c; c.f = f;
    unsigned u = c.u + 0x7fffu + ((c.u >> 16) & 1u);
    return (unsigned short)(u >> 16);
}
__device__ __forceinline__ unsigned fbits(float f) {
    union { float f; unsigned u; } c; c.f = f; return c.u;
}
__device__ __forceinline__ float fof(unsigned u) {
    union { unsigned u; float f; } c; c.u = u; return c.f;
}
__device__ __forceinline__ int swz(int l) { return l ^ ((l >> 3) & 6); }

// hi = trunc-bf16 (top 16 bits), lo = rtn-bf16 of residual. 8 floats -> 2x uint4.
__device__ __forceinline__ void cvt8(float4 A, float4 B, uint4& h, uint4& l) {
    unsigned a0 = fbits(A.x), a1 = fbits(A.y), a2 = fbits(A.z), a3 = fbits(A.w);
    unsigned b0 = fbits(B.x), b1 = fbits(B.y), b2 = fbits(B.z), b3 = fbits(B.w);
    h.x = __builtin_amdgcn_perm(a1, a0, 0x07060302u);
    h.y = __builtin_amdgcn_perm(a3, a2, 0x07060302u);
    h.z = __builtin_amdgcn_perm(b1, b0, 0x07060302u);
    h.w = __builtin_amdgcn_perm(b3, b2, 0x07060302u);
    unsigned l0 = fbits(A.x - fof(a0 & 0xffff0000u)) + 0x8000u;
    unsigned l1 = fbits(A.y - fof(a1 & 0xffff0000u)) + 0x8000u;
    unsigned l2 = fbits(A.z - fof(a2 & 0xffff0000u)) + 0x8000u;
    unsigned l3 = fbits(A.w - fof(a3 & 0xffff0000u)) + 0x8000u;
    unsigned m0 = fbits(B.x - fof(b0 & 0xffff0000u)) + 0x8000u;
    unsigned m1 = fbits(B.y - fof(b1 & 0xffff0000u)) + 0x8000u;
    unsigned m2 = fbits(B.z - fof(b2 & 0xffff0000u)) + 0x8000u;
    unsigned m3 = fbits(B.w - fof(b3 & 0xffff0000u)) + 0x8000u;
    l.x = __builtin_amdgcn_perm(l1, l0, 0x07060302u);
    l.y = __builtin_amdgcn_perm(l3, l2, 0x07060302u);
    l.z = __builtin_amdgcn_perm(m1, m0, 0x07060302u);
    l.w = __builtin_amdgcn_perm(m3, m2, 0x07060302u);
}
__device__ __forceinline__ float s4(float4 v) { return (v.x + v.y) + (v.z + v.w); }

// ---------------- Gram partials via bf16x3 MFMA, 2-phase pipelined -----------
// Also emits per-block row-sum partials of x and y (deterministic).
__global__ __launch_bounds__(256, 2) void k_gram(const float* __restrict__ x,
                                                 const float* __restrict__ y,
                                                 float* __restrict__ part,
                                                 float* __restrict__ sxp,
                                                 float* __restrict__ syp,
                                                 int nsplit) {
    int bid = blockIdx.x;
    int half = bid & 1;
    int ks = (bid >> 1) % nsplit;
    int b = bid / (2 * nsplit);
    int Kblk = Nn / nsplit;
    int nstep = Kblk >> 5;

    const float* X = x + (size_t)b * Cc * Nn + (size_t)(half * 128) * Nn + (size_t)ks * Kblk;
    const float* Y = y + (size_t)b * Cc * Nn + (size_t)ks * Kblk;

    __shared__ __align__(16) short XH[4096], XL[4096];
    __shared__ __align__(16) short YH[8192], YL[8192];

    int tid = threadIdx.x;
    int lane = tid & 63;
    int wave = tid >> 6;
    int wr = wave >> 1, wc = wave & 1;
    int r = tid >> 1, kh = tid & 1;

    const float* px  = X + (size_t)r * Nn + kh * 16;
    const float* py0 = Y + (size_t)r * Nn + kh * 16;
    const float* py1 = Y + (size_t)(r + 128) * Nn + kh * 16;

    int tr = r >> 4, rr = r & 15;
    int l0 = rr + 32 * kh, l1 = l0 + 16;
    int xo0 = (tr * 64 + swz(l0)) * 8, xo1 = (tr * 64 + swz(l1)) * 8;
    int yo00 = (tr * 64 + swz(l0)) * 8, yo01 = (tr * 64 + swz(l1)) * 8;
    int yo10 = ((tr + 8) * 64 + swz(l0)) * 8, yo11 = ((tr + 8) * 64 + swz(l1)) * 8;

    f32x4 acc[4][8];
    #pragma unroll
    for (int i = 0; i < 4; ++i)
        #pragma unroll
        for (int j = 0; j < 8; ++j)
            #pragma unroll
            for (int z = 0; z < 4; ++z) acc[i][j][z] = 0.f;

    float4 F[12];
    float xsum = 0.f, ysum0 = 0.f, ysum1 = 0.f;

    #define LOADF(kb) do { \
        F[0] = ((const float4*)(px  + (kb)))[0]; F[1] = ((const float4*)(px  + (kb)))[1]; \
        F[2] = ((const float4*)(px  + (kb)))[2]; F[3] = ((const float4*)(px  + (kb)))[3]; \
        F[4] = ((const float4*)(py0 + (kb)))[0]; F[5] = ((const float4*)(py0 + (kb)))[1]; \
        F[6] = ((const float4*)(py0 + (kb)))[2]; F[7] = ((const float4*)(py0 + (kb)))[3]; \
        F[8] = ((const float4*)(py1 + (kb)))[0]; F[9] = ((const float4*)(py1 + (kb)))[1]; \
        F[10] = ((const float4*)(py1 + (kb)))[2]; F[11] = ((const float4*)(py1 + (kb)))[3]; \
    } while (0)

    LOADF(0);
    for (int t = 0; t < nstep; ++t) {
        uint4 h0, h1, h2, h3, h4, h5, q0, q1, q2, q3, q4, q5;
        cvt8(F[0], F[1], h0, q0);  cvt8(F[2], F[3], h1, q1);
        cvt8(F[4], F[5], h2, q2);  cvt8(F[6], F[7], h3, q3);
        cvt8(F[8], F[9], h4, q4);  cvt8(F[10], F[11], h5, q5);
        xsum += s4(F[0]) + s4(F[1]) + s4(F[2]) + s4(F[3]);
        if (half == 0) {
            ysum0 += s4(F[4]) + s4(F[5]) + s4(F[6]) + s4(F[7]);
            ysum1 += s4(F[8]) + s4(F[9]) + s4(F[10]) + s4(F[11]);
        }
        __syncthreads();                 // previous compute finished reading LDS
        *(uint4*)&XH[xo0] = h0; *(uint4*)&XL[xo0] = q0;
        *(uint4*)&XH[xo1] = h1; *(uint4*)&XL[xo1] = q1;
        *(uint4*)&YH[yo00] = h2; *(uint4*)&YL[yo00] = q2;
        *(uint4*)&YH[yo01] = h3; *(uint4*)&YL[yo01] = q3;
        *(uint4*)&YH[yo10] = h4; *(uint4*)&YL[yo10] = q4;
        *(uint4*)&YH[yo11] = h5; *(uint4*)&YL[yo11] = q5;
        if (t + 1 < nstep) LOADF((t + 1) * 32);   // in flight under MFMA below
        __syncthreads();
        {
            int sl = swz(lane);
            s16x8 ah[4], al[4];
            #pragma unroll
            for (int i = 0; i < 4; ++i) {
                int fr = (wr * 4 + i) * 64 + sl;
                ah[i] = *(const s16x8*)&XH[fr * 8];
                al[i] = *(const s16x8*)&XL[fr * 8];
            }
            #pragma unroll
            for (int j = 0; j < 8; ++j) {
                int fr = (wc * 8 + j) * 64 + sl;
                s16x8 bh = *(const s16x8*)&YH[fr * 8];
                s16x8 bl = *(const s16x8*)&YL[fr * 8];
                #pragma unroll
                for (int i = 0; i < 4; ++i) {
                    acc[i][j] = __builtin_amdgcn_mfma_f32_16x16x32_bf16(ah[i], bh, acc[i][j], 0, 0, 0);
                    acc[i][j] = __builtin_amdgcn_mfma_f32_16x16x32_bf16(ah[i], bl, acc[i][j], 0, 0, 0);
                    acc[i][j] = __builtin_amdgcn_mfma_f32_16x16x32_bf16(al[i], bh, acc[i][j], 0, 0, 0);
                }
            }
        }
    }
    #undef LOADF

    // row-sum partials (deterministic): combine kh pair via shfl
    float xs  = xsum  + __shfl_down(xsum, 1);
    float y0s = ysum0 + __shfl_down(ysum0, 1);
    float y1s = ysum1 + __shfl_down(ysum1, 1);
    if (!(tid & 1)) {
        sxp[((size_t)b * nsplit + ks) * 256 + half * 128 + r] = xs;
        if (half == 0) {
            syp[((size_t)b * nsplit + ks) * 256 + r] = y0s;
            syp[((size_t)b * nsplit + ks) * 256 + 128 + r] = y1s;
        }
    }

    // write partials (C/D: col = lane&15, row = (lane>>4)*4 + reg)
    float* P = part + ((size_t)b * nsplit + ks) * Cc * Cc;
    #pragma unroll
    for (int i = 0; i < 4; ++i)
        #pragma unroll
        for (int j = 0; j < 8; ++j)
            #pragma unroll
            for (int reg = 0; reg < 4; ++reg) {
                int gi = half * 128 + wr * 64 + i * 16 + (lane >> 4) * 4 + reg;
                int gj = wc * 128 + j * 16 + (lane & 15);
                P[(size_t)gi * Cc + gj] = acc[i][j][reg];
            }
}

// reduce S partials; blocks >=1024 reduce row-sum partials into sx/sy
__global__ __launch_bounds__(256) void k_reduceS(const float* __restrict__ part,
                                                 const float* __restrict__ sxp,
                                                 const float* __restrict__ syp,
                                                 float* __restrict__ S,
                                                 float* __restrict__ sx,
                                                 float* __restrict__ sy, int split) {
    if (blockIdx.x < 1024) {
        int t = blockIdx.x * 256 + threadIdx.x;   // 0..262143
        int b = t >> 16;
        int rc = t & 65535;
        float s = 0.f;
        for (int ks = 0; ks < split; ++ks)
            s += part[(((size_t)b * split + ks) << 16) + rc];
        S[t] = s;
    } else {
        int flat = (blockIdx.x - 1024) * 256 + threadIdx.x;  // 0..2047
        int b = flat >> 9, rem = flat & 511, which = rem >> 8, c = rem & 255;
        const float* src = (which ? syp : sxp) + (size_t)b * split * 256 + c;
        float s = 0.f;
        for (int ks = 0; ks < split; ++ks) s += src[(size_t)ks * 256];
        (which ? sy : sx)[b * 256 + c] = s;
    }
}

// qx[b,i] = Wq[i,:]·sx[b,:];  ky[b,j] = Wk[j,:]·sy[b,:]
__global__ __launch_bounds__(256) void k_qxky(const float* __restrict__ Wq,
                                              const float* __restrict__ Wk,
                                              const float* __restrict__ sx,
                                              const float* __restrict__ sy,
                                              float* __restrict__ qx,
                                              float* __restrict__ ky) {
    int t = blockIdx.x * 256 + threadIdx.x;   // 0..2047
    int which = t >> 10;
    int b = (t >> 8) & 3;
    int r = t & 255;
    const float* W  = which ? Wk : Wq;
    const float* sv = which ? sy : sx;
    float* dst      = which ? ky : qx;
    float s = 0.f;
    #pragma unroll 4
    for (int c = 0; c < Cc; ++c) s += W[r * Cc + c] * sv[b * Cc + c];
    dst[b * Cc + r] = s;
}

// T1[b,c,j] = sum_d S[b,c,d] * Wk[j,d]
__global__ __launch_bounds__(256) void k_T1(const float* __restrict__ S,
                                            const float* __restrict__ Wk,
                                            float* __restrict__ T1) {
    int b = blockIdx.x >> 8;
    int c = blockIdx.x & 255;
    int j = threadIdx.x;
    __shared__ float srow[256];
    srow[j] = S[((size_t)b * Cc + c) * Cc + j];
    __syncthreads();
    const float4* wk4 = (const float4*)(Wk + (size_t)j * Cc);
    const float4* sr4 = (const float4*)srow;
    float s = 0.f;
    #pragma unroll 4
    for (int d = 0; d < Cc / 4; ++d) {
        float4 a = sr4[d]; float4 w = wk4[d];
        s += a.x * w.x + a.y * w.y + a.z * w.z + a.w * w.w;
    }
    T1[((size_t)b * Cc + c) * Cc + j] = s;
}

// scores + softmax + cbias:  one block per (b,i) row
__global__ __launch_bounds__(256) void k_scores_softmax(const float* __restrict__ T1,
                                                        const float* __restrict__ Wq,
                                                        const float* __restrict__ bq,
                                                        const float* __restrict__ bk,
                                                        const float* __restrict__ qx,
                                                        const float* __restrict__ ky,
                                                        const float* __restrict__ bv,
                                                        float* __restrict__ Wt,
                                                        float* __restrict__ cbias) {
    int b = blockIdx.x >> 8;
    int i = blockIdx.x & 255;
    int j = threadIdx.x;
    __shared__ float wq[256];
    wq[j] = Wq[i * Cc + j];
    __syncthreads();
    const float* t1 = T1 + (size_t)b * Cc * Cc + j;
    float s = 0.f;
    #pragma unroll 4
    for (int c = 0; c < Cc; ++c) s += wq[c] * t1[(size_t)c * Cc];
    s += qx[b * Cc + i] * bk[j] + bq[i] * (ky[b * Cc + j] + 32768.0f * bk[j]);

    __shared__ float red[256];
    red[j] = s; __syncthreads();
    for (int st = 128; st > 0; st >>= 1) {
        if (j < st) red[j] = fmaxf(red[j], red[j + st]);
        __syncthreads();
    }
    float mx = red[0];
    __syncthreads();
    float e = expf(s - mx);
    red[j] = e; __syncthreads();
    for (int st = 128; st > 0; st >>= 1) {
        if (j < st) red[j] += red[j + st];
        __syncthreads();
    }
    float w = e / red[0];
    Wt[((size_t)b * Cc + i) * Cc + j] = w;
    __syncthreads();
    red[j] = w * bv[j]; __syncthreads();
    for (int st = 128; st > 0; st >>= 1) {
        if (j < st) red[j] += red[j + st];
        __syncthreads();
    }
    if (j == 0) cbias[b * Cc + i] = red[0];
}

// M[b,i,c] = sum_j Wt[b,i,j] * Wv[j,c]   -> bf16
__global__ __launch_bounds__(256) void k_M(const float* __restrict__ Wt,
                                           const float* __restrict__ Wv,
                                           short* __restrict__ Mbf) {
    int b = blockIdx.x >> 8;
    int i = blockIdx.x & 255;
    int c = threadIdx.x;
    __shared__ float wrow[256];
    wrow[c] = Wt[((size_t)b * Cc + i) * Cc + c];
    __syncthreads();
    float m = 0.f;
    #pragma unroll 4
    for (int j = 0; j < Cc; ++j) m += wrow[j] * Wv[(size_t)j * Cc + c];
    Mbf[((size_t)b * Cc + i) * Cc + c] = (short)bfh(m);
}

// out[b,i,n] = sum_c M[b,i,c]*y[b,c,n] + cb[b,i]   (single-pass bf16 MFMA)
__global__ __launch_bounds__(256, 2) void k_out_mfma(const short* __restrict__ Mbf,
                                                     const float* __restrict__ y,
                                                     const float* __restrict__ cb,
                                                     float* __restrict__ out) {
    int tid = threadIdx.x;
    int lane = tid & 63;
    int wave = tid >> 6;
    int bid = blockIdx.x;           // 0..1023
    int b = bid >> 8, grp = bid & 255;
    int nbase = grp * 128 + wave * 32;
    const float* Y = y + (size_t)b * Cc * Nn;
    const short* M = Mbf + (size_t)b * Cc * Cc;

    f32x4 acc[16][2];
    #pragma unroll
    for (int ti = 0; ti < 16; ++ti)
        #pragma unroll
        for (int nb = 0; nb < 2; ++nb)
            #pragma unroll
            for (int z = 0; z < 4; ++z) acc[ti][nb][z] = 0.f;

    for (int s = 0; s < 8; ++s) {
        int c0 = 32 * s + 8 * (lane >> 4);
        s16x8 bf0, bf1;
        #pragma unroll
        for (int j = 0; j < 8; ++j) {
            float v0 = Y[(size_t)(c0 + j) * Nn + nbase + (lane & 15)];
            float v1 = Y[(size_t)(c0 + j) * Nn + nbase + 16 + (lane & 15)];
            bf0[j] = (short)bfh(v0);
            bf1[j] = (short)bfh(v1);
        }
        #pragma unroll
        for (int ti = 0; ti < 16; ++ti) {
            s16x8 af = *(const s16x8*)&M[(size_t)(ti * 16 + (lane & 15)) * Cc + c0];
            acc[ti][0] = __builtin_amdgcn_mfma_f32_16x16x32_bf16(af, bf0, acc[ti][0], 0, 0, 0);
            acc[ti][1] = __builtin_amdgcn_mfma_f32_16x16x32_bf16(af, bf1, acc[ti][1], 0, 0, 0);
        }
    }
    #pragma unroll
    for (int ti = 0; ti < 16; ++ti)
        #pragma unroll
        for (int nb = 0; nb < 2; ++nb)
            #pragma unroll
            for (int reg = 0; reg < 4; ++reg) {
                int i = ti * 16 + (lane >> 4) * 4 + reg;
                out[((size_t)b * Cc + i) * Nn + nbase + nb * 16 + (lane & 15)] =
                    acc[ti][nb][reg] + cb[b * Cc + i];
            }
}

extern "C" void kernel_launch(void* const* d_in, const int* in_sizes, int n_in,
                              void* d_out, int out_size, void* d_ws, size_t ws_size,
                              hipStream_t stream) {
    const float* x  = (const float*)d_in[0];
    const float* y  = (const float*)d_in[1];
    const float* Wq = (const float*)d_in[2];
    const float* bq = (const float*)d_in[3];
    const float* Wk = (const float*)d_in[4];
    const float* bk = (const float*)d_in[5];
    const float* Wv = (const float*)d_in[6];
    const float* bv = (const float*)d_in[7];
    float* out = (float*)d_out;

    float* ws = (float*)d_ws;
    size_t off = 0;
    float* S  = ws + off; off += (size_t)Bb * Cc * Cc;
    float* sx = ws + off; off += Bb * Cc;
    float* sy = ws + off; off += Bb * Cc;
    float* qx = ws + off; off += Bb * Cc;
    float* ky = ws + off; off += Bb * Cc;
    float* T1 = ws + off; off += (size_t)Bb * Cc * Cc;
    float* Wt = ws + off; off += (size_t)Bb * Cc * Cc;
    short* Mbf = (short*)(ws + off); off += (size_t)Bb * Cc * Cc / 2;
    float* cb = ws + off; off += Bb * Cc;
    float* sxp = ws + off; off += (size_t)Bb * 64 * 256;
    float* syp = ws + off; off += (size_t)Bb * 64 * 256;
    float* part = ws + off;

    size_t avail = ws_size / 4 - off;
    int split = 64;
    while (split > 16 && (size_t)split * Bb * Cc * Cc > avail) split >>= 1;

    k_gram<<<Bb * split * 2, 256, 0, stream>>>(x, y, part, sxp, syp, split);
    k_reduceS<<<1032, 256, 0, stream>>>(part, sxp, syp, S, sx, sy, split);
    k_qxky<<<8, 256, 0, stream>>>(Wq, Wk, sx, sy, qx, ky);
    k_T1<<<1024, 256, 0, stream>>>(S, Wk, T1);
    k_scores_softmax<<<1024, 256, 0, stream>>>(T1, Wq, bq, bk, qx, ky, bv, Wt, cb);
    k_M<<<1024, 256, 0, stream>>>(Wt, Wv, Mbf);
    k_out_mfma<<<1024, 256, 0, stream>>>(Mbf, y, cb, out);
}